// Round 1
// baseline (493.718 us; speedup 1.0000x reference)
//
#include <hip/hip_runtime.h>

// Problem constants: B=2, S=2048, E=1024, H=16, DH=64. All fp32 in/out.
// Pipeline:
//   1) convert q,k,v,Wq,Wk,Wv,Wo fp32->bf16              (1 launch)
//   2) Q = q @ Wq^T + bq  (bf16 NT-GEMM, 128x128 tile)   (3 launches)
//   3) V^T reshape [b][h][d][s] for PV B-fragments       (1 launch)
//   4) fused attention with cross-head logit mixing      (1 launch)
//      S'_g = sum_h M~[g,h] * (Q_h K_h^T), M~ = (I+Wc)/8; bc dropped
//      (constant along k => softmax-invariant). Online softmax, PV accum.
//   5) out = O @ Wo^T + bo, fp32 to d_out                (1 launch)
// Workspace layout (56 MB total, reuse: O overlays q_bf, VT overlays k_bf).

typedef __attribute__((ext_vector_type(8))) short bf16x8_t;   // 8 bf16 (4 VGPRs)
typedef __attribute__((ext_vector_type(4))) float f32x4_t;    // MFMA accumulator

__device__ inline unsigned short f2bf(float f) {
  unsigned u = __builtin_bit_cast(unsigned, f);
  u += 0x7fffu + ((u >> 16) & 1u);          // round-to-nearest-even
  return (unsigned short)(u >> 16);
}

struct ConvArgs {
  const float* src[7];
  unsigned short* dst[7];
  int n[7];
};

__global__ __launch_bounds__(256) void convert_f32_bf16(ConvArgs a) {
  const int which = blockIdx.y;
  const int i = (blockIdx.x * 256 + threadIdx.x) * 8;
  if (i >= a.n[which]) return;
  const float* s = a.src[which] + i;
  f32x4_t x0 = *(const f32x4_t*)(s);
  f32x4_t x1 = *(const f32x4_t*)(s + 4);
  bf16x8_t o;
#pragma unroll
  for (int j = 0; j < 4; j++) o[j] = (short)f2bf(x0[j]);
#pragma unroll
  for (int j = 0; j < 4; j++) o[4 + j] = (short)f2bf(x1[j]);
  *(bf16x8_t*)(a.dst[which] + i) = o;
}

// C[m][n] = sum_k A[m][k] * Bt[n][k] + bias[n].  M,N,K multiples of 128/128/32.
// 256 threads = 4 waves in 2x2; wave tile 64x64 = 4x4 frags of 16x16; BK=32.
__global__ __launch_bounds__(256) void gemm_bt(
    const unsigned short* __restrict__ A, const unsigned short* __restrict__ Bt,
    const float* __restrict__ bias, void* __restrict__ C,
    int M, int N, int K, int c_is_f32)
{
  __shared__ unsigned short As[128 * 32];
  __shared__ unsigned short Bs[128 * 32];
  const int t = threadIdx.x;
  const int l = t & 63;
  const int w = t >> 6;
  const int quad = l >> 4, n16 = l & 15;
  const int wm = (w & 1) * 64, wn = (w >> 1) * 64;
  const long m0 = (long)blockIdx.x * 128, n0 = (long)blockIdx.y * 128;

  f32x4_t acc[4][4] = {};

  // staging: thread t covers tile row t/4 (+64 on round 1), cols (t%4)*8..+7
  const unsigned short* gA = A + (m0 + (t >> 2)) * (long)K + (t & 3) * 8;
  const unsigned short* gB = Bt + (n0 + (t >> 2)) * (long)K + (t & 3) * 8;
  const long rowskip = 64l * K;

  for (int kt = 0; kt < K; kt += 32) {
    bf16x8_t ra0 = *(const bf16x8_t*)(gA + kt);
    bf16x8_t ra1 = *(const bf16x8_t*)(gA + kt + rowskip);
    bf16x8_t rb0 = *(const bf16x8_t*)(gB + kt);
    bf16x8_t rb1 = *(const bf16x8_t*)(gB + kt + rowskip);
    __syncthreads();                       // protect LDS from prior iter reads
    *(bf16x8_t*)&As[t * 8] = ra0;          // elem (t>>2)*32 + (t&3)*8 == t*8
    *(bf16x8_t*)&As[2048 + t * 8] = ra1;
    *(bf16x8_t*)&Bs[t * 8] = rb0;
    *(bf16x8_t*)&Bs[2048 + t * 8] = rb1;
    __syncthreads();                       // staging visible
    bf16x8_t af[4], bfr[4];
#pragma unroll
    for (int i = 0; i < 4; i++) {
      af[i]  = *(const bf16x8_t*)&As[(wm + i * 16 + n16) * 32 + quad * 8];
      bfr[i] = *(const bf16x8_t*)&Bs[(wn + i * 16 + n16) * 32 + quad * 8];
    }
#pragma unroll
    for (int mi = 0; mi < 4; mi++)
#pragma unroll
      for (int ni = 0; ni < 4; ni++)
        acc[mi][ni] = __builtin_amdgcn_mfma_f32_16x16x32_bf16(af[mi], bfr[ni], acc[mi][ni], 0, 0, 0);
  }

#pragma unroll
  for (int ni = 0; ni < 4; ni++) {
    const long n = n0 + wn + ni * 16 + n16;
    const float bv = bias[n];
#pragma unroll
    for (int mi = 0; mi < 4; mi++) {
#pragma unroll
      for (int r = 0; r < 4; r++) {
        const long m = m0 + wm + mi * 16 + quad * 4 + r;  // D: row=(l>>4)*4+reg, col=l&15
        const float v = acc[mi][ni][r] + bv;
        if (c_is_f32) ((float*)C)[m * N + n] = v;
        else ((unsigned short*)C)[m * N + n] = f2bf(v);
      }
    }
  }
}

// V [b][s][h*64+d] -> VT [b][h][d][s]
__global__ __launch_bounds__(256) void transpose_v(
    const unsigned short* __restrict__ V, unsigned short* __restrict__ VT)
{
  __shared__ unsigned short tile[64][72];   // +8 pad
  const int t = threadIdx.x;
  const int s0 = blockIdx.x * 64, h = blockIdx.y, b = blockIdx.z;
#pragma unroll
  for (int r = 0; r < 2; r++) {
    const int elem = r * 2048 + t * 8;
    const int s = elem >> 6, d = elem & 63;
    *(bf16x8_t*)&tile[s][d] =
        *(const bf16x8_t*)&V[(size_t)(b * 2048 + s0 + s) * 1024 + h * 64 + d];
  }
  __syncthreads();
#pragma unroll
  for (int r = 0; r < 2; r++) {
    const int elem = r * 2048 + t * 8;
    const int d = elem >> 6, sl = elem & 63;
    bf16x8_t o;
#pragma unroll
    for (int j = 0; j < 8; j++) o[j] = (short)tile[sl + j][d];
    *(bf16x8_t*)&VT[((size_t)(b * 16 + h) * 64 + d) * 2048 + s0 + sl] = o;
  }
}

// Fused attention. Grid (128 q-blocks, 2 batches). 1024 threads = 16 waves,
// wave g owns head g. Tq=16 query rows, Tk=32 keys per iteration.
// Per iter: QK^T (4 MFMA) -> sraw LDS (transposed, col-major, zero-padded h)
//   -> barrier -> head-mix via 16x16x32 MFMA (2 chunks/wave) -> sprime fp32
//   -> barrier -> online softmax -> P via LDS -> PV (4 MFMA).
__global__ __launch_bounds__(1024) void attention_fused(
    const unsigned short* __restrict__ Qb, const unsigned short* __restrict__ Kb,
    const unsigned short* __restrict__ VT, const float* __restrict__ Wc,
    unsigned short* __restrict__ Obuf)
{
  __shared__ unsigned short sraw[512 * 40];   // [col = q*32+k][hslot 0..39], 16B-aligned rows
  __shared__ float sprime[16 * 580];          // [g][q*36 + k], row stride 580 (bank-staggered)
  __shared__ unsigned short pbuf[16][16 * 40];// per-wave P [q][k], row stride 40
  __shared__ unsigned short mmat[16 * 32];    // M~ = (I+Wc)/8, zero-padded to h=32

  const int t = threadIdx.x;
  const int g = t >> 6, l = t & 63;
  const int quad = l >> 4, n16 = l & 15;
  const int qb = blockIdx.x, b = blockIdx.y;
  const int q0 = qb * 16;

  for (int i = t; i < 512 * 40; i += 1024) sraw[i] = 0;  // zero h-slots >=16 (read by MFMA pad)
  if (t < 256) {
    const int gg = t >> 4, hh = t & 15;
    const float v = (((gg == hh) ? 1.0f : 0.0f) + Wc[gg * 16 + hh]) * 0.125f;
    mmat[gg * 32 + hh] = f2bf(v);
  } else if (t < 512) {
    const int t2 = t - 256;
    mmat[(t2 >> 4) * 32 + 16 + (t2 & 15)] = 0;
  }
  __syncthreads();

  // mix A-frag: A[m=g_out=l&15][k=h=quad*8+j]
  const bf16x8_t mfrag = *(const bf16x8_t*)&mmat[n16 * 32 + quad * 8];
  // Q A-frags: A[m=q=l&15][k=d]
  bf16x8_t qf[2];
#pragma unroll
  for (int dr = 0; dr < 2; dr++)
    qf[dr] = *(const bf16x8_t*)&Qb[(size_t)(b * 2048 + q0 + n16) * 1024 + g * 64 + dr * 32 + quad * 8];

  f32x4_t o[4] = {};
  float m_run = -1e30f, l_run = 0.0f;
  const int qrow = l >> 2, kpos = (l & 3) * 8;  // softmax lane mapping: 4 lanes per q row

  for (int kt = 0; kt < 2048; kt += 32) {
    // K B-frags: B[n=key=l&15][k=d] ; V B-frags: B[n=d=l&15][k=key]
    bf16x8_t kf[2][2], vf[4];
#pragma unroll
    for (int kc = 0; kc < 2; kc++)
#pragma unroll
      for (int dr = 0; dr < 2; dr++)
        kf[kc][dr] = *(const bf16x8_t*)&Kb[(size_t)(b * 2048 + kt + kc * 16 + n16) * 1024
                                           + g * 64 + dr * 32 + quad * 8];
#pragma unroll
    for (int dc = 0; dc < 4; dc++)
      vf[dc] = *(const bf16x8_t*)&VT[((size_t)(b * 16 + g) * 64 + dc * 16 + n16) * 2048
                                      + kt + quad * 8];

    f32x4_t sfrag[2] = {};
#pragma unroll
    for (int kc = 0; kc < 2; kc++)
#pragma unroll
      for (int dr = 0; dr < 2; dr++)
        sfrag[kc] = __builtin_amdgcn_mfma_f32_16x16x32_bf16(qf[dr], kf[kc][dr], sfrag[kc], 0, 0, 0);

    // D: row=q=quad*4+r, col=key=n16. Write transposed: sraw[col][h=g]
#pragma unroll
    for (int kc = 0; kc < 2; kc++)
#pragma unroll
      for (int r = 0; r < 4; r++) {
        const int col = (quad * 4 + r) * 32 + kc * 16 + n16;
        sraw[col * 40 + g] = f2bf(sfrag[kc][r]);
      }
    __syncthreads();  // B1: sraw complete (also orders next-iter overwrites)

    // head mix: S'(16g x 512col) = M~(16x32,zero-pad) @ Sraw(32x512); 2 col-chunks/wave
    f32x4_t mixd[2];
#pragma unroll
    for (int c2 = 0; c2 < 2; c2++) {
      const int c = g * 2 + c2;
      const bf16x8_t bb = *(const bf16x8_t*)&sraw[(c * 16 + n16) * 40 + quad * 8];
      f32x4_t z = {};
      mixd[c2] = __builtin_amdgcn_mfma_f32_16x16x32_bf16(mfrag, bb, z, 0, 0, 0);
    }
#pragma unroll
    for (int c2 = 0; c2 < 2; c2++) {
      const int c = g * 2 + c2;
      const int qq = c >> 1;                 // chunk spans 16 cols inside one q row
      const int kk = (c & 1) * 16 + n16;
#pragma unroll
      for (int r = 0; r < 4; r++)
        sprime[(quad * 4 + r) * 580 + qq * 36 + kk] = mixd[c2][r];
    }
    __syncthreads();  // B2: sprime complete

    // online softmax on wave g's row: lane covers q=l>>2, keys kpos..kpos+7
    const float* rowp = &sprime[g * 580 + qrow * 36 + kpos];
    const f32x4_t x0 = *(const f32x4_t*)rowp;
    const f32x4_t x1 = *(const f32x4_t*)(rowp + 4);
    float mloc = fmaxf(fmaxf(fmaxf(x0[0], x0[1]), fmaxf(x0[2], x0[3])),
                       fmaxf(fmaxf(x1[0], x1[1]), fmaxf(x1[2], x1[3])));
    mloc = fmaxf(mloc, __shfl_xor(mloc, 1));
    mloc = fmaxf(mloc, __shfl_xor(mloc, 2));
    const float mnew = fmaxf(m_run, mloc);
    const float alpha = __expf(m_run - mnew);
    float sum = 0.0f;
    bf16x8_t pv8;
#pragma unroll
    for (int j = 0; j < 4; j++) {
      const float e = __expf(x0[j] - mnew);
      sum += e; pv8[j] = (short)f2bf(e);
    }
#pragma unroll
    for (int j = 0; j < 4; j++) {
      const float e = __expf(x1[j] - mnew);
      sum += e; pv8[4 + j] = (short)f2bf(e);
    }
    sum += __shfl_xor(sum, 1);
    sum += __shfl_xor(sum, 2);
    l_run = l_run * alpha + sum;
    m_run = mnew;
    *(bf16x8_t*)&pbuf[g][qrow * 40 + kpos] = pv8;   // wave-private, lockstep-safe

    // rescale O rows by alpha (row q = quad*4+r lives at source lane q*4)
#pragma unroll
    for (int r = 0; r < 4; r++) {
      const float ar = __shfl(alpha, (quad * 4 + r) * 4);
#pragma unroll
      for (int dc = 0; dc < 4; dc++) o[dc][r] *= ar;
    }

    // P A-frag: A[m=q=l&15][k=key=quad*8+j]
    const bf16x8_t pf = *(const bf16x8_t*)&pbuf[g][n16 * 40 + quad * 8];
#pragma unroll
    for (int dc = 0; dc < 4; dc++)
      o[dc] = __builtin_amdgcn_mfma_f32_16x16x32_bf16(pf, vf[dc], o[dc], 0, 0, 0);
  }

  float linv[4];
#pragma unroll
  for (int r = 0; r < 4; r++)
    linv[r] = 1.0f / __shfl(l_run, (quad * 4 + r) * 4);
#pragma unroll
  for (int dc = 0; dc < 4; dc++)
#pragma unroll
    for (int r = 0; r < 4; r++) {
      const float v = o[dc][r] * linv[r];
      Obuf[(size_t)(b * 2048 + q0 + quad * 4 + r) * 1024 + g * 64 + dc * 16 + n16] = f2bf(v);
    }
}

extern "C" void kernel_launch(void* const* d_in, const int* in_sizes, int n_in,
                              void* d_out, int out_size, void* d_ws, size_t ws_size,
                              hipStream_t stream) {
  const float* query = (const float*)d_in[0];
  const float* key   = (const float*)d_in[1];
  const float* value = (const float*)d_in[2];
  const float* Wq = (const float*)d_in[3];
  const float* bq = (const float*)d_in[4];
  const float* Wk = (const float*)d_in[5];
  const float* bk = (const float*)d_in[6];
  const float* Wv = (const float*)d_in[7];
  const float* bv = (const float*)d_in[8];
  const float* Wc = (const float*)d_in[9];
  // d_in[10] = bc: constant along softmax axis -> provably no effect on output
  const float* Wo = (const float*)d_in[11];
  const float* bo = (const float*)d_in[12];

  char* ws = (char*)d_ws;
  const size_t MB = 1024 * 1024;
  unsigned short* q_bf  = (unsigned short*)(ws);            // 8MB; later reused as Obuf
  unsigned short* k_bf  = (unsigned short*)(ws + 8 * MB);   // 8MB; later reused as VT
  unsigned short* v_bf  = (unsigned short*)(ws + 16 * MB);  // 8MB
  unsigned short* wq_bf = (unsigned short*)(ws + 24 * MB);  // 2MB
  unsigned short* wk_bf = (unsigned short*)(ws + 26 * MB);  // 2MB
  unsigned short* wv_bf = (unsigned short*)(ws + 28 * MB);  // 2MB
  unsigned short* wo_bf = (unsigned short*)(ws + 30 * MB);  // 2MB
  unsigned short* Qb    = (unsigned short*)(ws + 32 * MB);  // 8MB
  unsigned short* Kb    = (unsigned short*)(ws + 40 * MB);  // 8MB
  unsigned short* Vb    = (unsigned short*)(ws + 48 * MB);  // 8MB  (total 56MB)
  unsigned short* VT   = k_bf;   // k_bf dead after K-projection
  unsigned short* Obuf = q_bf;   // q_bf dead after Q-projection

  ConvArgs ca;
  ca.src[0] = query; ca.dst[0] = q_bf;  ca.n[0] = 2 * 2048 * 1024;
  ca.src[1] = key;   ca.dst[1] = k_bf;  ca.n[1] = 2 * 2048 * 1024;
  ca.src[2] = value; ca.dst[2] = v_bf;  ca.n[2] = 2 * 2048 * 1024;
  ca.src[3] = Wq;    ca.dst[3] = wq_bf; ca.n[3] = 1024 * 1024;
  ca.src[4] = Wk;    ca.dst[4] = wk_bf; ca.n[4] = 1024 * 1024;
  ca.src[5] = Wv;    ca.dst[5] = wv_bf; ca.n[5] = 1024 * 1024;
  ca.src[6] = Wo;    ca.dst[6] = wo_bf; ca.n[6] = 1024 * 1024;
  convert_f32_bf16<<<dim3(2048, 7), 256, 0, stream>>>(ca);

  gemm_bt<<<dim3(32, 8), 256, 0, stream>>>(q_bf, wq_bf, bq, Qb, 4096, 1024, 1024, 0);
  gemm_bt<<<dim3(32, 8), 256, 0, stream>>>(k_bf, wk_bf, bk, Kb, 4096, 1024, 1024, 0);
  gemm_bt<<<dim3(32, 8), 256, 0, stream>>>(v_bf, wv_bf, bv, Vb, 4096, 1024, 1024, 0);

  transpose_v<<<dim3(32, 16, 2), 256, 0, stream>>>(Vb, VT);

  attention_fused<<<dim3(128, 2), 1024, 0, stream>>>(Qb, Kb, VT, Wc, Obuf);

  gemm_bt<<<dim3(32, 8), 256, 0, stream>>>(Obuf, wo_bf, bo, d_out, 4096, 1024, 1024, 1);
}